// Round 6
// baseline (113.737 us; speedup 1.0000x reference)
//
#include <hip/hip_runtime.h>
#include <stdint.h>
#include <math.h>

// Multiresolution hash encoding, 16 levels.
// grids = {4,5,6,9,12,15,21,27,36,48,63,84,111,147,194,255}
// kh = 256//grid, P = floor(256/kh).
// K1 (fused, block ranges ordered heavy->light):
//   [0, PD)            levels 13..15 direct (kh=1, bilinear=identity), float3 gathers
//   [PD, PD+B2)        levels 9..12 thread-per-cell pooling -> fws
//   [PD+B2, ...)       levels 0..8 wave-per-cell pooling -> fws
// fws is stride-4 floats per cell (aligned float4).
// K2: levels 0..12 bilinear upsample, aligned float4 corner loads, float4 stores.

#define NLVL 16
#define NB   16

__constant__ int   c_P[NLVL]   = {4,5,6,9,12,15,21,28,36,51,64,85,128,256,256,256};
__constant__ int   c_KH[NLVL]  = {64,51,42,28,21,17,12,9,7,5,4,3,2,1,1,1};
__constant__ float c_G[NLVL]   = {4.f,5.f,6.f,9.f,12.f,15.f,21.f,27.f,36.f,48.f,63.f,84.f,111.f,147.f,194.f,255.f};
// prefix sums of P^2 for levels 0..12 (cells per batch), total 33354
__constant__ int   c_CUM[14]   = {0,16,41,77,158,302,527,968,1752,3048,5649,9745,16970,33354};

#define A_LVLS    9
#define A_CELLS   3048
#define A_BLOCKS  12192                     // A_CELLS*16/4
#define B2_FIRST  9
#define B2_CELLS  30306
#define B2_THREADS (B2_CELLS*NB)            // 484896
#define B2_BLOCKS ((B2_THREADS + 255)/256)  // 1895
#define PD_BLOCKS 1024
#define B2_BLK0   PD_BLOCKS                 // 1024
#define A_BLK0    (PD_BLOCKS + B2_BLOCKS)   // 2919
#define K1_BLOCKS (A_BLK0 + A_BLOCKS)       // 15111

__device__ __forceinline__ uint32_t hash3(float m0, float m1, float m2, float g) {
    uint32_t v0 = (uint32_t)(int)(m0 * g);
    uint32_t v1 = (uint32_t)(int)(m1 * g);
    uint32_t v2 = (uint32_t)(int)(m2 * g);
    return (v0 ^ (v1 * 2654435761u) ^ (v2 * 805459861u)) & 0xFFFFu;
}

// ---- K1 ----
__global__ __launch_bounds__(256) void pool_fused(const float* __restrict__ img,
                                                  const float* __restrict__ tab,
                                                  float* __restrict__ fws,
                                                  float* __restrict__ out)
{
    if (blockIdx.x < PD_BLOCKS) {
        // direct path, levels 13..15: identity bilinear, 4 px/thread, float3 gathers
        int t = blockIdx.x * 256 + threadIdx.x;     // 262144 total
        int b = t >> 14;
        int pix0 = (t & 16383) << 2;
        const float* p = img + (size_t)b * 196608 + pix0;
        float4 i0 = *(const float4*)p;
        float4 i1 = *(const float4*)(p + 65536);
        float4 i2 = *(const float4*)(p + 131072);
#pragma unroll
        for (int lvl = 13; lvl < 16; ++lvl) {
            float g = c_G[lvl];
            const float* T = tab + (size_t)lvl * 196608;
            uint32_t g0 = hash3(i0.x, i1.x, i2.x, g);
            uint32_t g1 = hash3(i0.y, i1.y, i2.y, g);
            uint32_t g2 = hash3(i0.z, i1.z, i2.z, g);
            uint32_t g3 = hash3(i0.w, i1.w, i2.w, g);
            float3 f0 = *(const float3*)(T + g0 * 3);
            float3 f1 = *(const float3*)(T + g1 * 3);
            float3 f2 = *(const float3*)(T + g2 * 3);
            float3 f3 = *(const float3*)(T + g3 * 3);
            float4 o0, o1, o2;
            o0.x = f0.x; o1.x = f0.y; o2.x = f0.z;
            o0.y = f1.x; o1.y = f1.y; o2.y = f1.z;
            o0.z = f2.x; o1.z = f2.y; o2.z = f2.z;
            o0.w = f3.x; o1.w = f3.y; o2.w = f3.z;
            float* ob = out + ((size_t)b * 48 + 3 * lvl) * 65536 + pix0;
            *(float4*)ob            = o0;
            *(float4*)(ob + 65536)  = o1;
            *(float4*)(ob + 131072) = o2;
        }
    } else if (blockIdx.x < A_BLK0) {
        // thread path, levels 9..12 (kh <= 5)
        int tid = (blockIdx.x - B2_BLK0) * 256 + threadIdx.x;
        if (tid >= B2_THREADS) return;
        int b = tid / B2_CELLS;
        int r = tid - b * B2_CELLS + A_CELLS;
        int lvl = B2_FIRST;
#pragma unroll
        for (int l = B2_FIRST + 1; l <= 12; ++l) lvl += (r >= c_CUM[l]);
        int P = c_P[lvl], kh = c_KH[lvl];
        int cell = r - c_CUM[lvl];
        int iy = cell / P, ix = cell - iy * P;

        const float* p = img + (size_t)b * 196608 + (size_t)(iy * kh) * 256 + ix * kh;
        float m0 = -INFINITY, m1 = -INFINITY, m2 = -INFINITY;
        for (int rr = 0; rr < kh; ++rr)
            for (int cc = 0; cc < kh; ++cc) {
                int o = rr * 256 + cc;
                m0 = fmaxf(m0, p[o]);
                m1 = fmaxf(m1, p[65536 + o]);
                m2 = fmaxf(m2, p[131072 + o]);
            }
        uint32_t gg = hash3(m0, m1, m2, c_G[lvl]);
        float3 tv = *(const float3*)(tab + (size_t)lvl * 196608 + gg * 3);
        float4 fv; fv.x = tv.x; fv.y = tv.y; fv.z = tv.z; fv.w = 0.f;
        *(float4*)(fws + ((size_t)c_CUM[lvl] * NB + (size_t)b * (P * P) + cell) * 4) = fv;
    } else {
        // wave path, levels 0..8: 2D lane map (col = lane%kh, row-group = lane/kh)
        int wid  = (blockIdx.x - A_BLK0) * 4 + (threadIdx.x >> 6);
        int lane = threadIdx.x & 63;
        int b = wid / A_CELLS;
        int r = wid - b * A_CELLS;
        int lvl = 0;
#pragma unroll
        for (int l = 1; l < A_LVLS; ++l) lvl += (r >= c_CUM[l]);
        int P = c_P[lvl], kh = c_KH[lvl];
        int cell = r - c_CUM[lvl];
        int iy = cell / P, ix = cell - iy * P;

        int G   = 64 / kh;
        int col = lane % kh;
        int grp = lane / kh;

        float m0 = -INFINITY, m1 = -INFINITY, m2 = -INFINITY;
        if (grp < G) {
            const float* p = img + (size_t)b * 196608 + (size_t)(iy * kh) * 256 + ix * kh + col;
            for (int rr = grp; rr < kh; rr += G) {
                int o = rr * 256;
                m0 = fmaxf(m0, p[o]);
                m1 = fmaxf(m1, p[65536 + o]);
                m2 = fmaxf(m2, p[131072 + o]);
            }
        }
#pragma unroll
        for (int off = 32; off > 0; off >>= 1) {
            m0 = fmaxf(m0, __shfl_xor(m0, off, 64));
            m1 = fmaxf(m1, __shfl_xor(m1, off, 64));
            m2 = fmaxf(m2, __shfl_xor(m2, off, 64));
        }
        if (lane == 0) {
            uint32_t gg = hash3(m0, m1, m2, c_G[lvl]);
            float3 tv = *(const float3*)(tab + (size_t)lvl * 196608 + gg * 3);
            float4 fv; fv.x = tv.x; fv.y = tv.y; fv.z = tv.z; fv.w = 0.f;
            *(float4*)(fws + ((size_t)c_CUM[lvl] * NB + (size_t)b * (P * P) + cell) * 4) = fv;
        }
    }
}

// ---- K2: levels 0..12 bilinear upsample, aligned float4 corner loads ----
// src = ((2o+1)*P - 256)/512 : exact int; frac exact in fp32.
__global__ __launch_bounds__(256) void upsample4(const float* __restrict__ fws,
                                                 float* __restrict__ out)
{
    int plane = blockIdx.y;          // lvl*16 + b, lvl in [0,13)
    int lvl   = plane >> 4;
    int b     = plane & 15;
    int P     = c_P[lvl];

    int w    = threadIdx.x >> 6;
    int lane = threadIdx.x & 63;
    int y    = blockIdx.x * 4 + w;

    int numy = (2 * y + 1) * P - 256;
    int iy0  = numy >> 9;
    float fy = (float)(numy & 511) * (1.0f / 512.0f);
    int iy1;
    if (iy0 < 0)           { iy0 = 0;     iy1 = 0;     fy = 0.f; }
    else if (iy0 >= P - 1) { iy0 = P - 1; iy1 = P - 1; fy = 0.f; }
    else                   { iy1 = iy0 + 1; }

    const float* fb = fws + ((size_t)c_CUM[lvl] * NB + (size_t)b * P * P) * 4;
    const float* r0 = fb + (size_t)iy0 * P * 4;
    const float* r1 = fb + (size_t)iy1 * P * 4;
    float wy0 = 1.f - fy, wy1 = fy;

    float v[3][4];
    int xb = lane << 2;
#pragma unroll
    for (int j = 0; j < 4; ++j) {
        int numx = (2 * (xb + j) + 1) * P - 256;
        int ix0  = numx >> 9;
        float fx = (float)(numx & 511) * (1.0f / 512.0f);
        int ix1;
        if (ix0 < 0)           { ix0 = 0;     ix1 = 0;     fx = 0.f; }
        else if (ix0 >= P - 1) { ix0 = P - 1; ix1 = P - 1; fx = 0.f; }
        else                   { ix1 = ix0 + 1; }
        float wx0 = 1.f - fx, wx1 = fx;
        float4 t00 = *(const float4*)(r0 + ix0 * 4);
        float4 t01 = *(const float4*)(r0 + ix1 * 4);
        float4 t10 = *(const float4*)(r1 + ix0 * 4);
        float4 t11 = *(const float4*)(r1 + ix1 * 4);
        v[0][j] = wy0 * (wx0 * t00.x + wx1 * t01.x) + wy1 * (wx0 * t10.x + wx1 * t11.x);
        v[1][j] = wy0 * (wx0 * t00.y + wx1 * t01.y) + wy1 * (wx0 * t10.y + wx1 * t11.y);
        v[2][j] = wy0 * (wx0 * t00.z + wx1 * t01.z) + wy1 * (wx0 * t10.z + wx1 * t11.z);
    }
    float* o = out + ((size_t)b * 48 + 3 * lvl) * 65536 + (size_t)y * 256 + xb;
#pragma unroll
    for (int c = 0; c < 3; ++c) {
        float4 q; q.x = v[c][0]; q.y = v[c][1]; q.z = v[c][2]; q.w = v[c][3];
        *(float4*)(o + (size_t)c * 65536) = q;
    }
}

extern "C" void kernel_launch(void* const* d_in, const int* in_sizes, int n_in,
                              void* d_out, int out_size, void* d_ws, size_t ws_size,
                              hipStream_t stream)
{
    const float* img = (const float*)d_in[0];   // (16,3,256,256) f32
    const float* tab = (const float*)d_in[1];   // (16,65536,3) f32
    float* out = (float*)d_out;                 // (16,48,256,256) f32
    float* fws = (float*)d_ws;                  // 33354*16*4 f32 = 8.54 MB

    hipLaunchKernelGGL(pool_fused, dim3(K1_BLOCKS), dim3(256), 0, stream, img, tab, fws, out);
    hipLaunchKernelGGL(upsample4,  dim3(64, 13 * 16), dim3(256), 0, stream, fws, out);
}

// Round 7
// 103.838 us; speedup vs baseline: 1.0953x; 1.0953x over previous
//
#include <hip/hip_runtime.h>
#include <stdint.h>
#include <math.h>

// Multiresolution hash encoding, 16 levels.
// grids = {4,5,6,9,12,15,21,27,36,48,63,84,111,147,194,255}
// kh = 256//grid, P = floor(256/kh).
// K1: pooling levels 0..12 -> fws (float4/cell, stride-4).
// K2: [0,1024)   levels 13..15 direct (kh=1, bilinear=identity), float3 gathers
//     [1024,...) 64x64 output tiles, source window staged in LDS, bilinear
//                corners read from LDS (off the VMEM/TA pipe).

#define NLVL 16
#define NB   16

__constant__ int   c_P[NLVL]   = {4,5,6,9,12,15,21,28,36,51,64,85,128,256,256,256};
__constant__ int   c_KH[NLVL]  = {64,51,42,28,21,17,12,9,7,5,4,3,2,1,1,1};
__constant__ float c_G[NLVL]   = {4.f,5.f,6.f,9.f,12.f,15.f,21.f,27.f,36.f,48.f,63.f,84.f,111.f,147.f,194.f,255.f};
// prefix sums of P^2 for levels 0..12 (cells per batch), total 33354
__constant__ int   c_CUM[14]   = {0,16,41,77,158,302,527,968,1752,3048,5649,9745,16970,33354};

#define A_LVLS    9
#define A_CELLS   3048
#define A_BLOCKS  12192                     // A_CELLS*16/4
#define B2_FIRST  9
#define B2_CELLS  30306
#define B2_THREADS (B2_CELLS*NB)            // 484896
#define B2_BLOCKS ((B2_THREADS + 255)/256)  // 1895
#define K1_BLOCKS (B2_BLOCKS + A_BLOCKS)    // 14087

#define DIR_BLOCKS  1024
#define TILE_BLOCKS (13*16*16)              // 3328
#define K2_BLOCKS   (DIR_BLOCKS + TILE_BLOCKS)

__device__ __forceinline__ uint32_t hash3(float m0, float m1, float m2, float g) {
    uint32_t v0 = (uint32_t)(int)(m0 * g);
    uint32_t v1 = (uint32_t)(int)(m1 * g);
    uint32_t v2 = (uint32_t)(int)(m2 * g);
    return (v0 ^ (v1 * 2654435761u) ^ (v2 * 805459861u)) & 0xFFFFu;
}

// ---- K1: pooling levels 0..12 ----
__global__ __launch_bounds__(256) void pool_all(const float* __restrict__ img,
                                                const float* __restrict__ tab,
                                                float* __restrict__ fws)
{
    if (blockIdx.x < B2_BLOCKS) {
        // thread path, levels 9..12 (kh <= 5)
        int tid = blockIdx.x * 256 + threadIdx.x;
        if (tid >= B2_THREADS) return;
        int b = tid / B2_CELLS;
        int r = tid - b * B2_CELLS + A_CELLS;
        int lvl = B2_FIRST;
#pragma unroll
        for (int l = B2_FIRST + 1; l <= 12; ++l) lvl += (r >= c_CUM[l]);
        int P = c_P[lvl], kh = c_KH[lvl];
        int cell = r - c_CUM[lvl];
        int iy = cell / P, ix = cell - iy * P;

        const float* p = img + (size_t)b * 196608 + (size_t)(iy * kh) * 256 + ix * kh;
        float m0 = -INFINITY, m1 = -INFINITY, m2 = -INFINITY;
        for (int rr = 0; rr < kh; ++rr)
            for (int cc = 0; cc < kh; ++cc) {
                int o = rr * 256 + cc;
                m0 = fmaxf(m0, p[o]);
                m1 = fmaxf(m1, p[65536 + o]);
                m2 = fmaxf(m2, p[131072 + o]);
            }
        uint32_t gg = hash3(m0, m1, m2, c_G[lvl]);
        float3 tv = *(const float3*)(tab + (size_t)lvl * 196608 + gg * 3);
        float4 fv; fv.x = tv.x; fv.y = tv.y; fv.z = tv.z; fv.w = 0.f;
        *(float4*)(fws + ((size_t)c_CUM[lvl] * NB + (size_t)b * (P * P) + cell) * 4) = fv;
    } else {
        // wave path, levels 0..8: 2D lane map (col = lane%kh, row-group = lane/kh)
        int wid  = (blockIdx.x - B2_BLOCKS) * 4 + (threadIdx.x >> 6);
        int lane = threadIdx.x & 63;
        int b = wid / A_CELLS;
        int r = wid - b * A_CELLS;
        int lvl = 0;
#pragma unroll
        for (int l = 1; l < A_LVLS; ++l) lvl += (r >= c_CUM[l]);
        int P = c_P[lvl], kh = c_KH[lvl];
        int cell = r - c_CUM[lvl];
        int iy = cell / P, ix = cell - iy * P;

        int G   = 64 / kh;
        int col = lane % kh;
        int grp = lane / kh;

        float m0 = -INFINITY, m1 = -INFINITY, m2 = -INFINITY;
        if (grp < G) {
            const float* p = img + (size_t)b * 196608 + (size_t)(iy * kh) * 256 + ix * kh + col;
            for (int rr = grp; rr < kh; rr += G) {
                int o = rr * 256;
                m0 = fmaxf(m0, p[o]);
                m1 = fmaxf(m1, p[65536 + o]);
                m2 = fmaxf(m2, p[131072 + o]);
            }
        }
#pragma unroll
        for (int off = 32; off > 0; off >>= 1) {
            m0 = fmaxf(m0, __shfl_xor(m0, off, 64));
            m1 = fmaxf(m1, __shfl_xor(m1, off, 64));
            m2 = fmaxf(m2, __shfl_xor(m2, off, 64));
        }
        if (lane == 0) {
            uint32_t gg = hash3(m0, m1, m2, c_G[lvl]);
            float3 tv = *(const float3*)(tab + (size_t)lvl * 196608 + gg * 3);
            float4 fv; fv.x = tv.x; fv.y = tv.y; fv.z = tv.z; fv.w = 0.f;
            *(float4*)(fws + ((size_t)c_CUM[lvl] * NB + (size_t)b * (P * P) + cell) * 4) = fv;
        }
    }
}

// ---- K2: direct levels 13..15 + LDS-tiled bilinear for levels 0..12 ----
// src = ((2o+1)*P - 256)/512 : exact int; frac exact in fp32.
__global__ __launch_bounds__(256) void render(const float* __restrict__ img,
                                              const float* __restrict__ tab,
                                              const float* __restrict__ fws,
                                              float* __restrict__ out)
{
    __shared__ float4 s[34 * 34];
    if (blockIdx.x < DIR_BLOCKS) {
        // direct path, levels 13..15: identity bilinear, 4 px/thread
        int t = blockIdx.x * 256 + threadIdx.x;     // 262144 total
        int b = t >> 14;
        int pix0 = (t & 16383) << 2;
        const float* p = img + (size_t)b * 196608 + pix0;
        float4 i0 = *(const float4*)p;
        float4 i1 = *(const float4*)(p + 65536);
        float4 i2 = *(const float4*)(p + 131072);
#pragma unroll
        for (int lvl = 13; lvl < 16; ++lvl) {
            float g = c_G[lvl];
            const float* T = tab + (size_t)lvl * 196608;
            uint32_t g0 = hash3(i0.x, i1.x, i2.x, g);
            uint32_t g1 = hash3(i0.y, i1.y, i2.y, g);
            uint32_t g2 = hash3(i0.z, i1.z, i2.z, g);
            uint32_t g3 = hash3(i0.w, i1.w, i2.w, g);
            float3 f0 = *(const float3*)(T + g0 * 3);
            float3 f1 = *(const float3*)(T + g1 * 3);
            float3 f2 = *(const float3*)(T + g2 * 3);
            float3 f3 = *(const float3*)(T + g3 * 3);
            float4 o0, o1, o2;
            o0.x = f0.x; o1.x = f0.y; o2.x = f0.z;
            o0.y = f1.x; o1.y = f1.y; o2.y = f1.z;
            o0.z = f2.x; o1.z = f2.y; o2.z = f2.z;
            o0.w = f3.x; o1.w = f3.y; o2.w = f3.z;
            float* ob = out + ((size_t)b * 48 + 3 * lvl) * 65536 + pix0;
            *(float4*)ob            = o0;
            *(float4*)(ob + 65536)  = o1;
            *(float4*)(ob + 131072) = o2;
        }
        return;
    }

    // tile path: 64x64 output tile of plane (lvl,b), source window in LDS
    int blk   = blockIdx.x - DIR_BLOCKS;
    int tile  = blk & 15;
    int plane = blk >> 4;            // 0..207
    int lvl   = plane >> 4;
    int b     = plane & 15;
    int P     = c_P[lvl];
    int yt0   = (tile >> 2) * 64;
    int xt0   = (tile & 3) * 64;

    // source window [r_lo..r_hi] x [c_lo..c_hi]
    int nlo  = ((2 * yt0 + 1) * P - 256) >> 9;
    int r_lo = nlo < 0 ? 0 : (nlo > P - 1 ? P - 1 : nlo);
    int nhi  = (((2 * (yt0 + 63) + 1) * P - 256) >> 9) + 1;
    int r_hi = nhi < 0 ? 0 : (nhi > P - 1 ? P - 1 : nhi);
    int mlo  = ((2 * xt0 + 1) * P - 256) >> 9;
    int c_lo = mlo < 0 ? 0 : (mlo > P - 1 ? P - 1 : mlo);
    int mhi  = (((2 * (xt0 + 63) + 1) * P - 256) >> 9) + 1;
    int c_hi = mhi < 0 ? 0 : (mhi > P - 1 ? P - 1 : mhi);
    int span_y = r_hi - r_lo + 1;
    int span_x = c_hi - c_lo + 1;

    const float4* fb4 = (const float4*)fws + (size_t)c_CUM[lvl] * NB + (size_t)b * P * P;
    int n = span_y * span_x;
    for (int t = threadIdx.x; t < n; t += 256) {
        int r = t / span_x, c = t - r * span_x;
        s[t] = fb4[(size_t)(r_lo + r) * P + c_lo + c];
    }
    __syncthreads();

    int lane = threadIdx.x & 63;
    int w    = threadIdx.x >> 6;
    int xq   = lane & 15;
    int rg   = lane >> 4;
    int xb   = xt0 + xq * 4;

    // x-corner data for the 4 px
    int ix0t[4], ix1t[4]; float wx1t[4];
#pragma unroll
    for (int j = 0; j < 4; ++j) {
        int numx = (2 * (xb + j) + 1) * P - 256;
        int ix0  = numx >> 9;
        float fx = (float)(numx & 511) * (1.0f / 512.0f);
        int ix1;
        if (ix0 < 0)           { ix0 = 0;     ix1 = 0;     fx = 0.f; }
        else if (ix0 >= P - 1) { ix0 = P - 1; ix1 = P - 1; fx = 0.f; }
        else                   { ix1 = ix0 + 1; }
        ix0t[j] = ix0 - c_lo; ix1t[j] = ix1 - c_lo; wx1t[j] = fx;
    }

#pragma unroll
    for (int k = 0; k < 4; ++k) {
        int y = yt0 + w * 16 + rg * 4 + k;
        int numy = (2 * y + 1) * P - 256;
        int iy0  = numy >> 9;
        float fy = (float)(numy & 511) * (1.0f / 512.0f);
        int iy1;
        if (iy0 < 0)           { iy0 = 0;     iy1 = 0;     fy = 0.f; }
        else if (iy0 >= P - 1) { iy0 = P - 1; iy1 = P - 1; fy = 0.f; }
        else                   { iy1 = iy0 + 1; }
        const float4* p0 = s + (iy0 - r_lo) * span_x;
        const float4* p1 = s + (iy1 - r_lo) * span_x;
        float wy1 = fy, wy0 = 1.f - fy;

        float v[3][4];
#pragma unroll
        for (int j = 0; j < 4; ++j) {
            float wx1 = wx1t[j], wx0 = 1.f - wx1;
            float4 t00 = p0[ix0t[j]];
            float4 t01 = p0[ix1t[j]];
            float4 t10 = p1[ix0t[j]];
            float4 t11 = p1[ix1t[j]];
            v[0][j] = wy0 * (wx0 * t00.x + wx1 * t01.x) + wy1 * (wx0 * t10.x + wx1 * t11.x);
            v[1][j] = wy0 * (wx0 * t00.y + wx1 * t01.y) + wy1 * (wx0 * t10.y + wx1 * t11.y);
            v[2][j] = wy0 * (wx0 * t00.z + wx1 * t01.z) + wy1 * (wx0 * t10.z + wx1 * t11.z);
        }
        float* o = out + ((size_t)b * 48 + 3 * lvl) * 65536 + (size_t)y * 256 + xb;
#pragma unroll
        for (int c = 0; c < 3; ++c) {
            float4 q; q.x = v[c][0]; q.y = v[c][1]; q.z = v[c][2]; q.w = v[c][3];
            *(float4*)(o + (size_t)c * 65536) = q;
        }
    }
}

extern "C" void kernel_launch(void* const* d_in, const int* in_sizes, int n_in,
                              void* d_out, int out_size, void* d_ws, size_t ws_size,
                              hipStream_t stream)
{
    const float* img = (const float*)d_in[0];   // (16,3,256,256) f32
    const float* tab = (const float*)d_in[1];   // (16,65536,3) f32
    float* out = (float*)d_out;                 // (16,48,256,256) f32
    float* fws = (float*)d_ws;                  // 33354*16*4 f32 = 8.54 MB

    hipLaunchKernelGGL(pool_all, dim3(K1_BLOCKS), dim3(256), 0, stream, img, tab, fws);
    hipLaunchKernelGGL(render,   dim3(K2_BLOCKS), dim3(256), 0, stream, img, tab, fws, out);
}

// Round 8
// 84.029 us; speedup vs baseline: 1.3536x; 1.2357x over previous
//
#include <hip/hip_runtime.h>
#include <stdint.h>
#include <math.h>

// Multiresolution hash encoding, 16 levels.
// grids = {4,5,6,9,12,15,21,27,36,48,63,84,111,147,194,255}
// kh = 256//grid, P = floor(256/kh).
// K0: zero mws (max workspace).
// K1: single-pass pooling: stage 8x256x3 band in LDS, compute all 13 levels'
//     cell maxima via col-partials + reduction, atomicMax (floats >= 0).
// K2: hash maxima + gather table -> fws (float4/cell).
// K3: render = direct levels 13..15 (kh=1, identity bilinear) + LDS-tiled
//     bilinear upsample for levels 0..12.

#define NLVL 16
#define NB   16

__constant__ int   c_P[NLVL]   = {4,5,6,9,12,15,21,28,36,51,64,85,128,256,256,256};
__constant__ float c_G[NLVL]   = {4.f,5.f,6.f,9.f,12.f,15.f,21.f,27.f,36.f,48.f,63.f,84.f,111.f,147.f,194.f,255.f};
__constant__ int   c_CUM[14]   = {0,16,41,77,158,302,527,968,1752,3048,5649,9745,16970,33354};

#define CELLS_PB   33354                 // cells/batch, levels 0..12
#define CELLS_TOT  (CELLS_PB*NB)         // 533664
#define MWS_FLOATS (CELLS_TOT*3)         // 1600992
#define POOL_BLOCKS (NB*32)              // (batch, 8-row band)
#define HG_BLOCKS  ((CELLS_TOT+255)/256) // 2085
#define DIR_BLOCKS  1024
#define TILE_BLOCKS (13*16*16)           // 3328
#define K3_BLOCKS   (DIR_BLOCKS + TILE_BLOCKS)

__device__ __forceinline__ uint32_t hash3(float m0, float m1, float m2, float g) {
    uint32_t v0 = (uint32_t)(int)(m0 * g);
    uint32_t v1 = (uint32_t)(int)(m1 * g);
    uint32_t v2 = (uint32_t)(int)(m2 * g);
    return (v0 ^ (v1 * 2654435761u) ^ (v2 * 805459861u)) & 0xFFFFu;
}

// ---- K0: zero the max workspace ----
__global__ __launch_bounds__(256) void zero_mws(float4* __restrict__ mws4)
{
    int t = blockIdx.x * 256 + threadIdx.x;
    if (t < MWS_FLOATS / 4) mws4[t] = make_float4(0.f, 0.f, 0.f, 0.f);
}

// ---- K1: single-pass pooling, all 13 levels from one image read ----
__global__ __launch_bounds__(256) void pool_single(const float* __restrict__ img,
                                                   unsigned int* __restrict__ mws)
{
    static constexpr int K_P[13]   = {4,5,6,9,12,15,21,28,36,51,64,85,128};
    static constexpr int K_KH[13]  = {64,51,42,28,21,17,12,9,7,5,4,3,2};
    static constexpr int K_CUM[13] = {0,16,41,77,158,302,527,968,1752,3048,5649,9745,16970};

    __shared__ float simg[3][8][256];
    __shared__ float colbuf[3][256];

    int b    = blockIdx.x >> 5;
    int band = blockIdx.x & 31;
    int y0   = band * 8;

    const float* base = img + (size_t)b * 196608 + (size_t)y0 * 256;
    for (int t = threadIdx.x; t < 1536; t += 256) {      // 1536 float4 = 3ch x 8rows x 256
        int ch = t >> 9;                                 // 512 float4 per channel
        int r  = t & 511;
        float4 v = *(const float4*)(base + (size_t)ch * 65536 + r * 4);
        int row = r >> 6, c4 = (r & 63) << 2;
        simg[ch][row][c4 + 0] = v.x;
        simg[ch][row][c4 + 1] = v.y;
        simg[ch][row][c4 + 2] = v.z;
        simg[ch][row][c4 + 3] = v.w;
    }
    __syncthreads();

    int x = threadIdx.x;
#pragma unroll
    for (int lvl = 0; lvl < 13; ++lvl) {
        const int kh = K_KH[lvl], P = K_P[lvl];
        int nr0 = y0 / kh;
        int nr1 = (y0 + 7) / kh; if (nr1 > P - 1) nr1 = P - 1;
        for (int cr = nr0; cr <= nr1; ++cr) {
            int rlo = cr * kh;      if (rlo < y0) rlo = y0;
            int rhi = cr * kh + kh; if (rhi > y0 + 8) rhi = y0 + 8;
            float p0 = -INFINITY, p1 = -INFINITY, p2 = -INFINITY;
            for (int r = rlo; r < rhi; ++r) {
                int rr = r - y0;
                p0 = fmaxf(p0, simg[0][rr][x]);
                p1 = fmaxf(p1, simg[1][rr][x]);
                p2 = fmaxf(p2, simg[2][rr][x]);
            }
            colbuf[0][x] = p0; colbuf[1][x] = p1; colbuf[2][x] = p2;
            __syncthreads();
            if (x < P) {
                float q0 = -INFINITY, q1 = -INFINITY, q2 = -INFINITY;
                for (int c = x * kh; c < x * kh + kh; ++c) {
                    q0 = fmaxf(q0, colbuf[0][c]);
                    q1 = fmaxf(q1, colbuf[1][c]);
                    q2 = fmaxf(q2, colbuf[2][c]);
                }
                int idx = K_CUM[lvl] * NB + b * P * P + cr * P + x;
                atomicMax(&mws[idx],                 __float_as_uint(q0));
                atomicMax(&mws[idx + CELLS_TOT],     __float_as_uint(q1));
                atomicMax(&mws[idx + 2 * CELLS_TOT], __float_as_uint(q2));
            }
            __syncthreads();
        }
    }
}

// ---- K2: hash maxima + gather table features -> fws ----
__global__ __launch_bounds__(256) void hashgather(const float* __restrict__ mws,
                                                  const float* __restrict__ tab,
                                                  float* __restrict__ fws)
{
    static constexpr int K_CUM16[13] = {0,256,656,1232,2528,4832,8432,15488,28032,48768,90384,155920,271520};
    int tid = blockIdx.x * 256 + threadIdx.x;
    if (tid >= CELLS_TOT) return;
    int lvl = 0;
#pragma unroll
    for (int l = 1; l < 13; ++l) lvl += (tid >= K_CUM16[l]);
    float m0 = mws[tid];
    float m1 = mws[tid + CELLS_TOT];
    float m2 = mws[tid + 2 * CELLS_TOT];
    uint32_t g = hash3(m0, m1, m2, c_G[lvl]);
    float3 tv = *(const float3*)(tab + (size_t)lvl * 196608 + g * 3);
    float4 fv; fv.x = tv.x; fv.y = tv.y; fv.z = tv.z; fv.w = 0.f;
    *(float4*)(fws + (size_t)tid * 4) = fv;
}

// ---- K3: direct levels 13..15 + LDS-tiled bilinear for levels 0..12 ----
// src = ((2o+1)*P - 256)/512 : exact int; frac exact in fp32.
__global__ __launch_bounds__(256) void render(const float* __restrict__ img,
                                              const float* __restrict__ tab,
                                              const float* __restrict__ fws,
                                              float* __restrict__ out)
{
    __shared__ float4 s[34 * 34];
    if (blockIdx.x < DIR_BLOCKS) {
        int t = blockIdx.x * 256 + threadIdx.x;     // 262144 total
        int b = t >> 14;
        int pix0 = (t & 16383) << 2;
        const float* p = img + (size_t)b * 196608 + pix0;
        float4 i0 = *(const float4*)p;
        float4 i1 = *(const float4*)(p + 65536);
        float4 i2 = *(const float4*)(p + 131072);
#pragma unroll
        for (int lvl = 13; lvl < 16; ++lvl) {
            float g = c_G[lvl];
            const float* T = tab + (size_t)lvl * 196608;
            uint32_t g0 = hash3(i0.x, i1.x, i2.x, g);
            uint32_t g1 = hash3(i0.y, i1.y, i2.y, g);
            uint32_t g2 = hash3(i0.z, i1.z, i2.z, g);
            uint32_t g3 = hash3(i0.w, i1.w, i2.w, g);
            float3 f0 = *(const float3*)(T + g0 * 3);
            float3 f1 = *(const float3*)(T + g1 * 3);
            float3 f2 = *(const float3*)(T + g2 * 3);
            float3 f3 = *(const float3*)(T + g3 * 3);
            float4 o0, o1, o2;
            o0.x = f0.x; o1.x = f0.y; o2.x = f0.z;
            o0.y = f1.x; o1.y = f1.y; o2.y = f1.z;
            o0.z = f2.x; o1.z = f2.y; o2.z = f2.z;
            o0.w = f3.x; o1.w = f3.y; o2.w = f3.z;
            float* ob = out + ((size_t)b * 48 + 3 * lvl) * 65536 + pix0;
            *(float4*)ob            = o0;
            *(float4*)(ob + 65536)  = o1;
            *(float4*)(ob + 131072) = o2;
        }
        return;
    }

    int blk   = blockIdx.x - DIR_BLOCKS;
    int tile  = blk & 15;
    int plane = blk >> 4;            // 0..207
    int lvl   = plane >> 4;
    int b     = plane & 15;
    int P     = c_P[lvl];
    int yt0   = (tile >> 2) * 64;
    int xt0   = (tile & 3) * 64;

    int nlo  = ((2 * yt0 + 1) * P - 256) >> 9;
    int r_lo = nlo < 0 ? 0 : (nlo > P - 1 ? P - 1 : nlo);
    int nhi  = (((2 * (yt0 + 63) + 1) * P - 256) >> 9) + 1;
    int r_hi = nhi < 0 ? 0 : (nhi > P - 1 ? P - 1 : nhi);
    int mlo  = ((2 * xt0 + 1) * P - 256) >> 9;
    int c_lo = mlo < 0 ? 0 : (mlo > P - 1 ? P - 1 : mlo);
    int mhi  = (((2 * (xt0 + 63) + 1) * P - 256) >> 9) + 1;
    int c_hi = mhi < 0 ? 0 : (mhi > P - 1 ? P - 1 : mhi);
    int span_y = r_hi - r_lo + 1;
    int span_x = c_hi - c_lo + 1;

    const float4* fb4 = (const float4*)fws + (size_t)c_CUM[lvl] * NB + (size_t)b * P * P;
    int n = span_y * span_x;
    for (int t = threadIdx.x; t < n; t += 256) {
        int r = t / span_x, c = t - r * span_x;
        s[t] = fb4[(size_t)(r_lo + r) * P + c_lo + c];
    }
    __syncthreads();

    int lane = threadIdx.x & 63;
    int w    = threadIdx.x >> 6;
    int xq   = lane & 15;
    int rg   = lane >> 4;
    int xb   = xt0 + xq * 4;

    int ix0t[4], ix1t[4]; float wx1t[4];
#pragma unroll
    for (int j = 0; j < 4; ++j) {
        int numx = (2 * (xb + j) + 1) * P - 256;
        int ix0  = numx >> 9;
        float fx = (float)(numx & 511) * (1.0f / 512.0f);
        int ix1;
        if (ix0 < 0)           { ix0 = 0;     ix1 = 0;     fx = 0.f; }
        else if (ix0 >= P - 1) { ix0 = P - 1; ix1 = P - 1; fx = 0.f; }
        else                   { ix1 = ix0 + 1; }
        ix0t[j] = ix0 - c_lo; ix1t[j] = ix1 - c_lo; wx1t[j] = fx;
    }

#pragma unroll
    for (int k = 0; k < 4; ++k) {
        int y = yt0 + w * 16 + rg * 4 + k;
        int numy = (2 * y + 1) * P - 256;
        int iy0  = numy >> 9;
        float fy = (float)(numy & 511) * (1.0f / 512.0f);
        int iy1;
        if (iy0 < 0)           { iy0 = 0;     iy1 = 0;     fy = 0.f; }
        else if (iy0 >= P - 1) { iy0 = P - 1; iy1 = P - 1; fy = 0.f; }
        else                   { iy1 = iy0 + 1; }
        const float4* p0 = s + (iy0 - r_lo) * span_x;
        const float4* p1 = s + (iy1 - r_lo) * span_x;
        float wy1 = fy, wy0 = 1.f - fy;

        float v[3][4];
#pragma unroll
        for (int j = 0; j < 4; ++j) {
            float wx1 = wx1t[j], wx0 = 1.f - wx1;
            float4 t00 = p0[ix0t[j]];
            float4 t01 = p0[ix1t[j]];
            float4 t10 = p1[ix0t[j]];
            float4 t11 = p1[ix1t[j]];
            v[0][j] = wy0 * (wx0 * t00.x + wx1 * t01.x) + wy1 * (wx0 * t10.x + wx1 * t11.x);
            v[1][j] = wy0 * (wx0 * t00.y + wx1 * t01.y) + wy1 * (wx0 * t10.y + wx1 * t11.y);
            v[2][j] = wy0 * (wx0 * t00.z + wx1 * t01.z) + wy1 * (wx0 * t10.z + wx1 * t11.z);
        }
        float* o = out + ((size_t)b * 48 + 3 * lvl) * 65536 + (size_t)y * 256 + xb;
#pragma unroll
        for (int c = 0; c < 3; ++c) {
            float4 q; q.x = v[c][0]; q.y = v[c][1]; q.z = v[c][2]; q.w = v[c][3];
            *(float4*)(o + (size_t)c * 65536) = q;
        }
    }
}

extern "C" void kernel_launch(void* const* d_in, const int* in_sizes, int n_in,
                              void* d_out, int out_size, void* d_ws, size_t ws_size,
                              hipStream_t stream)
{
    const float* img = (const float*)d_in[0];   // (16,3,256,256) f32
    const float* tab = (const float*)d_in[1];   // (16,65536,3) f32
    float* out = (float*)d_out;                 // (16,48,256,256) f32
    float* mws = (float*)d_ws;                  // 1,600,992 f32 = 6.4 MB
    float* fws = mws + MWS_FLOATS;              // 533,664*4 f32 = 8.54 MB

    hipLaunchKernelGGL(zero_mws,    dim3((MWS_FLOATS/4 + 255)/256), dim3(256), 0, stream, (float4*)mws);
    hipLaunchKernelGGL(pool_single, dim3(POOL_BLOCKS), dim3(256), 0, stream, img, (unsigned int*)mws);
    hipLaunchKernelGGL(hashgather,  dim3(HG_BLOCKS), dim3(256), 0, stream, mws, tab, fws);
    hipLaunchKernelGGL(render,      dim3(K3_BLOCKS), dim3(256), 0, stream, img, tab, fws, out);
}

// Round 9
// 82.488 us; speedup vs baseline: 1.3788x; 1.0187x over previous
//
#include <hip/hip_runtime.h>
#include <stdint.h>
#include <math.h>

// Multiresolution hash encoding, 16 levels.
// grids = {4,5,6,9,12,15,21,27,36,48,63,84,111,147,194,255}
// kh = 256//grid, P = floor(256/kh).
// memset: mws = 0 (maxima workspace; image in [0,1) => max >= 0).
// K1: single-pass pooling: stage 8x256x3 band in LDS, all 13 levels' cell
//     maxima via col-partials + reduction, atomicMax (float-as-uint, >=0).
// K2: render = direct levels 13..15 (kh=1, identity bilinear) + LDS-tiled
//     bilinear for levels 0..12, with hash+table-gather fused into staging.

#define NLVL 16
#define NB   16

__constant__ int   c_P[NLVL]   = {4,5,6,9,12,15,21,28,36,51,64,85,128,256,256,256};
__constant__ float c_G[NLVL]   = {4.f,5.f,6.f,9.f,12.f,15.f,21.f,27.f,36.f,48.f,63.f,84.f,111.f,147.f,194.f,255.f};
__constant__ int   c_CUM[14]   = {0,16,41,77,158,302,527,968,1752,3048,5649,9745,16970,33354};

#define CELLS_PB   33354                 // cells/batch, levels 0..12
#define CELLS_TOT  (CELLS_PB*NB)         // 533664
#define MWS_FLOATS (CELLS_TOT*3)         // 1600992
#define POOL_BLOCKS (NB*32)              // (batch, 8-row band)
#define DIR_BLOCKS  1024
#define TILE_BLOCKS (13*16*16)           // 3328
#define K2_BLOCKS   (DIR_BLOCKS + TILE_BLOCKS)

__device__ __forceinline__ uint32_t hash3(float m0, float m1, float m2, float g) {
    uint32_t v0 = (uint32_t)(int)(m0 * g);
    uint32_t v1 = (uint32_t)(int)(m1 * g);
    uint32_t v2 = (uint32_t)(int)(m2 * g);
    return (v0 ^ (v1 * 2654435761u) ^ (v2 * 805459861u)) & 0xFFFFu;
}

// ---- K1: single-pass pooling, all 13 levels from one image read ----
__global__ __launch_bounds__(256) void pool_single(const float* __restrict__ img,
                                                   unsigned int* __restrict__ mws)
{
    static constexpr int K_P[13]   = {4,5,6,9,12,15,21,28,36,51,64,85,128};
    static constexpr int K_KH[13]  = {64,51,42,28,21,17,12,9,7,5,4,3,2};
    static constexpr int K_CUM[13] = {0,16,41,77,158,302,527,968,1752,3048,5649,9745,16970};

    __shared__ float simg[3][8][256];
    __shared__ float colbuf[3][256];

    int b    = blockIdx.x >> 5;
    int band = blockIdx.x & 31;
    int y0   = band * 8;

    const float* base = img + (size_t)b * 196608 + (size_t)y0 * 256;
    for (int t = threadIdx.x; t < 1536; t += 256) {      // 1536 float4 = 3ch x 8rows x 256
        int ch = t >> 9;
        int r  = t & 511;
        float4 v = *(const float4*)(base + (size_t)ch * 65536 + r * 4);
        int row = r >> 6, c4 = (r & 63) << 2;
        simg[ch][row][c4 + 0] = v.x;
        simg[ch][row][c4 + 1] = v.y;
        simg[ch][row][c4 + 2] = v.z;
        simg[ch][row][c4 + 3] = v.w;
    }
    __syncthreads();

    int x = threadIdx.x;
#pragma unroll
    for (int lvl = 0; lvl < 13; ++lvl) {
        const int kh = K_KH[lvl], P = K_P[lvl];
        int nr0 = y0 / kh;
        int nr1 = (y0 + 7) / kh; if (nr1 > P - 1) nr1 = P - 1;
        for (int cr = nr0; cr <= nr1; ++cr) {
            int rlo = cr * kh;      if (rlo < y0) rlo = y0;
            int rhi = cr * kh + kh; if (rhi > y0 + 8) rhi = y0 + 8;
            float p0 = -INFINITY, p1 = -INFINITY, p2 = -INFINITY;
            for (int r = rlo; r < rhi; ++r) {
                int rr = r - y0;
                p0 = fmaxf(p0, simg[0][rr][x]);
                p1 = fmaxf(p1, simg[1][rr][x]);
                p2 = fmaxf(p2, simg[2][rr][x]);
            }
            colbuf[0][x] = p0; colbuf[1][x] = p1; colbuf[2][x] = p2;
            __syncthreads();
            if (x < P) {
                float q0 = -INFINITY, q1 = -INFINITY, q2 = -INFINITY;
                for (int c = x * kh; c < x * kh + kh; ++c) {
                    q0 = fmaxf(q0, colbuf[0][c]);
                    q1 = fmaxf(q1, colbuf[1][c]);
                    q2 = fmaxf(q2, colbuf[2][c]);
                }
                int idx = K_CUM[lvl] * NB + b * P * P + cr * P + x;
                atomicMax(&mws[idx],                 __float_as_uint(q0));
                atomicMax(&mws[idx + CELLS_TOT],     __float_as_uint(q1));
                atomicMax(&mws[idx + 2 * CELLS_TOT], __float_as_uint(q2));
            }
            __syncthreads();
        }
    }
}

// ---- K2: direct levels 13..15 + LDS-tiled bilinear (hash+gather fused) ----
// src = ((2o+1)*P - 256)/512 : exact int; frac exact in fp32.
__global__ __launch_bounds__(256) void render(const float* __restrict__ img,
                                              const float* __restrict__ tab,
                                              const float* __restrict__ mws,
                                              float* __restrict__ out)
{
    __shared__ float4 s[34 * 34];
    if (blockIdx.x < DIR_BLOCKS) {
        int t = blockIdx.x * 256 + threadIdx.x;     // 262144 total
        int b = t >> 14;
        int pix0 = (t & 16383) << 2;
        const float* p = img + (size_t)b * 196608 + pix0;
        float4 i0 = *(const float4*)p;
        float4 i1 = *(const float4*)(p + 65536);
        float4 i2 = *(const float4*)(p + 131072);
#pragma unroll
        for (int lvl = 13; lvl < 16; ++lvl) {
            float g = c_G[lvl];
            const float* T = tab + (size_t)lvl * 196608;
            uint32_t g0 = hash3(i0.x, i1.x, i2.x, g);
            uint32_t g1 = hash3(i0.y, i1.y, i2.y, g);
            uint32_t g2 = hash3(i0.z, i1.z, i2.z, g);
            uint32_t g3 = hash3(i0.w, i1.w, i2.w, g);
            float3 f0 = *(const float3*)(T + g0 * 3);
            float3 f1 = *(const float3*)(T + g1 * 3);
            float3 f2 = *(const float3*)(T + g2 * 3);
            float3 f3 = *(const float3*)(T + g3 * 3);
            float4 o0, o1, o2;
            o0.x = f0.x; o1.x = f0.y; o2.x = f0.z;
            o0.y = f1.x; o1.y = f1.y; o2.y = f1.z;
            o0.z = f2.x; o1.z = f2.y; o2.z = f2.z;
            o0.w = f3.x; o1.w = f3.y; o2.w = f3.z;
            float* ob = out + ((size_t)b * 48 + 3 * lvl) * 65536 + pix0;
            *(float4*)ob            = o0;
            *(float4*)(ob + 65536)  = o1;
            *(float4*)(ob + 131072) = o2;
        }
        return;
    }

    int blk   = blockIdx.x - DIR_BLOCKS;
    int tile  = blk & 15;
    int plane = blk >> 4;            // 0..207
    int lvl   = plane >> 4;
    int b     = plane & 15;
    int P     = c_P[lvl];
    int yt0   = (tile >> 2) * 64;
    int xt0   = (tile & 3) * 64;

    int nlo  = ((2 * yt0 + 1) * P - 256) >> 9;
    int r_lo = nlo < 0 ? 0 : (nlo > P - 1 ? P - 1 : nlo);
    int nhi  = (((2 * (yt0 + 63) + 1) * P - 256) >> 9) + 1;
    int r_hi = nhi < 0 ? 0 : (nhi > P - 1 ? P - 1 : nhi);
    int mlo  = ((2 * xt0 + 1) * P - 256) >> 9;
    int c_lo = mlo < 0 ? 0 : (mlo > P - 1 ? P - 1 : mlo);
    int mhi  = (((2 * (xt0 + 63) + 1) * P - 256) >> 9) + 1;
    int c_hi = mhi < 0 ? 0 : (mhi > P - 1 ? P - 1 : mhi);
    int span_y = r_hi - r_lo + 1;
    int span_x = c_hi - c_lo + 1;

    // stage: read maxima, hash, gather table feature per window cell
    int planebase = c_CUM[lvl] * NB + b * P * P;
    const float* T = tab + (size_t)lvl * 196608;
    float gmul = c_G[lvl];
    int n = span_y * span_x;
    for (int t = threadIdx.x; t < n; t += 256) {
        int r = t / span_x, c = t - r * span_x;
        int idx = planebase + (r_lo + r) * P + c_lo + c;
        float m0 = mws[idx];
        float m1 = mws[idx + CELLS_TOT];
        float m2 = mws[idx + 2 * CELLS_TOT];
        uint32_t g = hash3(m0, m1, m2, gmul);
        float3 tv = *(const float3*)(T + g * 3);
        float4 fv; fv.x = tv.x; fv.y = tv.y; fv.z = tv.z; fv.w = 0.f;
        s[t] = fv;
    }
    __syncthreads();

    int lane = threadIdx.x & 63;
    int w    = threadIdx.x >> 6;
    int xq   = lane & 15;
    int rg   = lane >> 4;
    int xb   = xt0 + xq * 4;

    int ix0t[4], ix1t[4]; float wx1t[4];
#pragma unroll
    for (int j = 0; j < 4; ++j) {
        int numx = (2 * (xb + j) + 1) * P - 256;
        int ix0  = numx >> 9;
        float fx = (float)(numx & 511) * (1.0f / 512.0f);
        int ix1;
        if (ix0 < 0)           { ix0 = 0;     ix1 = 0;     fx = 0.f; }
        else if (ix0 >= P - 1) { ix0 = P - 1; ix1 = P - 1; fx = 0.f; }
        else                   { ix1 = ix0 + 1; }
        ix0t[j] = ix0 - c_lo; ix1t[j] = ix1 - c_lo; wx1t[j] = fx;
    }

#pragma unroll
    for (int k = 0; k < 4; ++k) {
        int y = yt0 + w * 16 + rg * 4 + k;
        int numy = (2 * y + 1) * P - 256;
        int iy0  = numy >> 9;
        float fy = (float)(numy & 511) * (1.0f / 512.0f);
        int iy1;
        if (iy0 < 0)           { iy0 = 0;     iy1 = 0;     fy = 0.f; }
        else if (iy0 >= P - 1) { iy0 = P - 1; iy1 = P - 1; fy = 0.f; }
        else                   { iy1 = iy0 + 1; }
        const float4* p0 = s + (iy0 - r_lo) * span_x;
        const float4* p1 = s + (iy1 - r_lo) * span_x;
        float wy1 = fy, wy0 = 1.f - fy;

        float v[3][4];
#pragma unroll
        for (int j = 0; j < 4; ++j) {
            float wx1 = wx1t[j], wx0 = 1.f - wx1;
            float4 t00 = p0[ix0t[j]];
            float4 t01 = p0[ix1t[j]];
            float4 t10 = p1[ix0t[j]];
            float4 t11 = p1[ix1t[j]];
            v[0][j] = wy0 * (wx0 * t00.x + wx1 * t01.x) + wy1 * (wx0 * t10.x + wx1 * t11.x);
            v[1][j] = wy0 * (wx0 * t00.y + wx1 * t01.y) + wy1 * (wx0 * t10.y + wx1 * t11.y);
            v[2][j] = wy0 * (wx0 * t00.z + wx1 * t01.z) + wy1 * (wx0 * t10.z + wx1 * t11.z);
        }
        float* o = out + ((size_t)b * 48 + 3 * lvl) * 65536 + (size_t)y * 256 + xb;
#pragma unroll
        for (int c = 0; c < 3; ++c) {
            float4 q; q.x = v[c][0]; q.y = v[c][1]; q.z = v[c][2]; q.w = v[c][3];
            *(float4*)(o + (size_t)c * 65536) = q;
        }
    }
}

extern "C" void kernel_launch(void* const* d_in, const int* in_sizes, int n_in,
                              void* d_out, int out_size, void* d_ws, size_t ws_size,
                              hipStream_t stream)
{
    const float* img = (const float*)d_in[0];   // (16,3,256,256) f32
    const float* tab = (const float*)d_in[1];   // (16,65536,3) f32
    float* out = (float*)d_out;                 // (16,48,256,256) f32
    float* mws = (float*)d_ws;                  // 1,600,992 f32 = 6.4 MB

    hipMemsetAsync(mws, 0, (size_t)MWS_FLOATS * sizeof(float), stream);
    hipLaunchKernelGGL(pool_single, dim3(POOL_BLOCKS), dim3(256), 0, stream, img, (unsigned int*)mws);
    hipLaunchKernelGGL(render,      dim3(K2_BLOCKS), dim3(256), 0, stream, img, tab, mws, out);
}